// Round 7
// baseline (375.855 us; speedup 1.0000x reference)
//
#include <hip/hip_runtime.h>
#include <hip/hip_bf16.h>

// B=4, N=2048, C=768, H=16, D=48. FP32 in/out.
// ws: Q,K,V [b][h][n][48] bf16 (Q pre-scaled by SCALE*log2e), Vt [b][h][d][n] bf16,
//     Y fp32. out = (y @ Wo^T + bo) + y + x,  y = attn_out + x
#define B_ 4
#define N_ 2048
#define C_ 768
#define H_ 16
#define D_ 48
#define SCALE_ 0.14433756729740643f
#define LOG2E_ 1.44269504088896f

using bf16 = __hip_bfloat16;
using bf16x8 = __attribute__((ext_vector_type(8))) short;
using f32x4  = __attribute__((ext_vector_type(4))) float;
using f32x16 = __attribute__((ext_vector_type(16))) float;

__device__ __forceinline__ unsigned short f2b(float f) {
  bf16 h = __float2bfloat16(f);
  return *reinterpret_cast<unsigned short*>(&h);
}
__device__ __forceinline__ unsigned int pack2(float lo, float hi) {
  return (unsigned int)f2b(lo) | ((unsigned int)f2b(hi) << 16);
}
__device__ __forceinline__ uint4 ld8f_cvt(const float* p) {
  float4 a = *reinterpret_cast<const float4*>(p);
  float4 b = *reinterpret_cast<const float4*>(p + 4);
  uint4 u;
  u.x = pack2(a.x, a.y); u.y = pack2(a.z, a.w);
  u.z = pack2(b.x, b.y); u.w = pack2(b.z, b.w);
  return u;
}

constexpr int TM = 128, TN = 128, TK = 32;

// ---- Kernel 1: QKV projection, MFMA. z picks Q/K/V. All write [b][h][n][48].
__global__ __launch_bounds__(256) void gemm_qkv(
    const float* __restrict__ X,
    const float* __restrict__ wq, const float* __restrict__ bq,
    const float* __restrict__ wk, const float* __restrict__ bk,
    const float* __restrict__ wv, const float* __restrict__ bv,
    bf16* __restrict__ Q, bf16* __restrict__ K, bf16* __restrict__ V)
{
  const float* W; const float* bias; bf16* dst;
  if (blockIdx.z == 0)      { W = wq; bias = bq; dst = Q; }
  else if (blockIdx.z == 1) { W = wk; bias = bk; dst = K; }
  else                      { W = wv; bias = bv; dst = V; }
  const float sc = (blockIdx.z == 0) ? (SCALE_ * LOG2E_) : 1.0f;

  __shared__ __align__(16) bf16 As[TM * TK];
  __shared__ __align__(16) bf16 Bs[TN * TK];

  const int tid  = threadIdx.x;
  const int lane = tid & 63, wid = tid >> 6;
  const int wm = (wid >> 1) * 64, wn = (wid & 1) * 64;
  const int row0 = blockIdx.y * TM, col0 = blockIdx.x * TN;
  const int mb = lane & 15;
  const int kq = (lane >> 4) * 8;

  f32x4 acc[4][4];
#pragma unroll
  for (int i = 0; i < 4; ++i)
#pragma unroll
    for (int j = 0; j < 4; ++j) acc[i][j] = (f32x4){0.f, 0.f, 0.f, 0.f};

  for (int k0 = 0; k0 < C_; k0 += TK) {
#pragma unroll
    for (int t = 0; t < 2; ++t) {
      const int c = t * 256 + tid;
      const int row = c >> 2, kc = (c & 3) * 8;
      ((uint4*)As)[c] = ld8f_cvt(X + (size_t)(row0 + row) * C_ + k0 + kc);
      ((uint4*)Bs)[c] = ld8f_cvt(W + (size_t)(col0 + row) * C_ + k0 + kc);
    }
    __syncthreads();
    bf16x8 af[4], bfr[4];
#pragma unroll
    for (int i = 0; i < 4; ++i)
      af[i] = *(const bf16x8*)(As + (wm + i * 16 + mb) * TK + kq);
#pragma unroll
    for (int j = 0; j < 4; ++j)
      bfr[j] = *(const bf16x8*)(Bs + (wn + j * 16 + mb) * TK + kq);
#pragma unroll
    for (int i = 0; i < 4; ++i)
#pragma unroll
      for (int j = 0; j < 4; ++j)
        acc[i][j] = __builtin_amdgcn_mfma_f32_16x16x32_bf16(af[i], bfr[j], acc[i][j], 0, 0, 0);
    __syncthreads();
  }

  const int crow = (lane >> 4) * 4;
#pragma unroll
  for (int j = 0; j < 4; ++j) {
    const int o = col0 + wn + j * 16 + mb;
    const int h = o / D_, d = o % D_;
    const float bb = bias[o];
#pragma unroll
    for (int i = 0; i < 4; ++i) {
#pragma unroll
      for (int reg = 0; reg < 4; ++reg) {
        const int r = row0 + wm + i * 16 + crow + reg;
        const int b_ = r >> 11, n = r & (N_ - 1);
        dst[(((size_t)(b_ * H_ + h)) * N_ + n) * D_ + d] =
            __float2bfloat16((acc[i][j][reg] + bb) * sc);
      }
    }
  }
}

// ---- Kernel 1b: V [bh][n][48] -> Vt [bh][d][n], coalesced both sides via LDS.
__global__ __launch_bounds__(256) void v_transpose(
    const bf16* __restrict__ V, bf16* __restrict__ Vt)
{
  __shared__ short T[64 * 57];   // odd stride: conflict-free column reads
  const int bh = blockIdx.x;
  const int t0 = blockIdx.y * 64;
  const int tid = threadIdx.x;
  const size_t slab = (size_t)bh * (N_ * D_);
  for (int cc = tid; cc < 384; cc += 256) {
    const int r = cc / 6, col = (cc % 6) * 8;
    bf16x8 v = *(const bf16x8*)(V + slab + (size_t)(t0 + r) * D_ + col);
#pragma unroll
    for (int e = 0; e < 8; ++e) T[r * 57 + col + e] = v[e];
  }
  __syncthreads();
  const size_t oslab = (size_t)bh * ((size_t)D_ * N_);
  const int p = tid & 31;        // n-pair index
  const int d0 = tid >> 5;       // 0..7
#pragma unroll
  for (int d = d0; d < D_; d += 8) {
    const unsigned int lo = (unsigned short)T[(2 * p)     * 57 + d];
    const unsigned int hi = (unsigned short)T[(2 * p + 1) * 57 + d];
    *(unsigned int*)(Vt + oslab + (size_t)d * N_ + t0 + 2 * p) = lo | (hi << 16);
  }
}

// ---- Kernel 2: barrier-free register flash attention.
// 1 wave = 32 q-rows. S^T via 32x32x16 (K-frags global->reg, zero d-padding),
// PV via 16x16x32 (V-frags global->reg from Vt). LDS only for per-wave P.
__global__ __launch_bounds__(256) void attn_mfma(
    const bf16* __restrict__ Q, const bf16* __restrict__ K,
    const bf16* __restrict__ Vt, const float* __restrict__ x,
    float* __restrict__ Y)
{
  __shared__ __align__(16) bf16 Ps[4 * 32 * 72];   // per-wave P [qrow][key]

  const int tid  = threadIdx.x;
  const int lane = tid & 63, wid = tid >> 6;
  const int g2 = lane >> 5;          // 0..1  (32x32 k-half)
  const int m5 = lane & 31;          // 0..31 (32x32 m/n index)
  const int g4 = lane >> 4;          // 0..3  (16x16 k-quad)  -- full range
  const int c  = lane & 15;          // 0..15 (16x16 m/n index)
  const int bh = blockIdx.x;
  const int b_ = bh >> 4, h = bh & 15;
  const int q0 = blockIdx.y * 128 + wid * 32;
  const size_t slab  = (size_t)bh * (N_ * D_);
  const size_t vslab = (size_t)bh * ((size_t)D_ * N_);
  bf16* Pw = Ps + wid * (32 * 72);

  // Q B-fragments (32x32x16): n=lane&31=qrow, k=(lane>>5)*8+j; kc = k-chunk of 16
  bf16x8 qf[3];
#pragma unroll
  for (int kc = 0; kc < 3; ++kc)
    qf[kc] = *(const bf16x8*)(Q + slab + (size_t)(q0 + m5) * D_ + kc * 16 + 8 * g2);

  f32x4 Oacc[2][3];
#pragma unroll
  for (int s = 0; s < 2; ++s)
#pragma unroll
    for (int df = 0; df < 3; ++df) Oacc[s][df] = (f32x4){0.f, 0.f, 0.f, 0.f};
  float lsum = 0.f;

  for (int k0 = 0; k0 < N_; k0 += 64) {
    // K A-fragments: m=lane&31=key(+32*mt), k=(lane>>5)*8+j (+16*kc)
    bf16x8 kf[2][3];
#pragma unroll
    for (int mt = 0; mt < 2; ++mt)
#pragma unroll
      for (int kc = 0; kc < 3; ++kc)
        kf[mt][kc] = *(const bf16x8*)(K + slab +
            (size_t)(k0 + mt * 32 + m5) * D_ + kc * 16 + 8 * g2);
    // V B-fragments (16x16x32): n=lane&15=dcol(+16*df), k=(lane>>4)*8+j (+32*hf)
    bf16x8 vf[3][2];
#pragma unroll
    for (int df = 0; df < 3; ++df)
#pragma unroll
      for (int hf = 0; hf < 2; ++hf)
        vf[df][hf] = *(const bf16x8*)(Vt + vslab +
            (size_t)(df * 16 + c) * N_ + k0 + hf * 32 + 8 * g4);

    // S^T = K·Q^T : D[m=key][n=qrow], 2 m-tiles x 3 k-chunks, no padding
    f32x16 st[2];
#pragma unroll
    for (int mt = 0; mt < 2; ++mt) {
      f32x16 z;
#pragma unroll
      for (int r = 0; r < 16; ++r) z[r] = 0.f;
      st[mt] = __builtin_amdgcn_mfma_f32_32x32x16_bf16(kf[mt][0], qf[0], z, 0, 0, 0);
      st[mt] = __builtin_amdgcn_mfma_f32_32x32x16_bf16(kf[mt][1], qf[1], st[mt], 0, 0, 0);
      st[mt] = __builtin_amdgcn_mfma_f32_32x32x16_bf16(kf[mt][2], qf[2], st[mt], 0, 0, 0);
    }
    // P = exp2(score) (scale*log2e folded into Q); lane holds qrow=m5,
    // keys = (r&3) + 8*(r>>2) + 4*g2 + 32*mt
    float psum = 0.f;
#pragma unroll
    for (int mt = 0; mt < 2; ++mt)
#pragma unroll
      for (int r = 0; r < 16; ++r) {
        st[mt][r] = __builtin_amdgcn_exp2f(st[mt][r]);
        psum += st[mt][r];
      }
    lsum += psum;   // per-lane; other key-half lives at lane^32, folded at end
    // pack P -> LDS [qrow][key]: regs 4q..4q+3 = keys 8q+4g2+0..3
#pragma unroll
    for (int mt = 0; mt < 2; ++mt)
#pragma unroll
      for (int q = 0; q < 4; ++q) {
        uint2 w;
        w.x = pack2(st[mt][4 * q + 0], st[mt][4 * q + 1]);
        w.y = pack2(st[mt][4 * q + 2], st[mt][4 * q + 3]);
        *(uint2*)(Pw + m5 * 72 + mt * 32 + 8 * q + 4 * g2) = w;
      }
    // PV: A = P [m=qrow 16(+16s)][k=key], B = vf
#pragma unroll
    for (int s = 0; s < 2; ++s) {
      bf16x8 pf[2];
#pragma unroll
      for (int hf = 0; hf < 2; ++hf)
        pf[hf] = *(const bf16x8*)(Pw + (s * 16 + c) * 72 + hf * 32 + 8 * g4);
#pragma unroll
      for (int df = 0; df < 3; ++df) {
        Oacc[s][df] = __builtin_amdgcn_mfma_f32_16x16x32_bf16(pf[0], vf[df][0], Oacc[s][df], 0, 0, 0);
        Oacc[s][df] = __builtin_amdgcn_mfma_f32_16x16x32_bf16(pf[1], vf[df][1], Oacc[s][df], 0, 0, 0);
      }
    }
  }

  // epilogue: l per qrow = lsum(lane qrow) + lsum(lane qrow^32)
  const float ltot = lsum + __shfl_xor(lsum, 32, 64);
#pragma unroll
  for (int s = 0; s < 2; ++s) {
#pragma unroll
    for (int r = 0; r < 4; ++r) {
      const float inv = 1.f / __shfl(ltot, s * 16 + 4 * g4 + r, 64);
      const int n = q0 + s * 16 + 4 * g4 + r;
      const size_t off = ((size_t)(b_ * N_ + n)) * C_ + h * D_ + c;
#pragma unroll
      for (int df = 0; df < 3; ++df)
        Y[off + df * 16] = Oacc[s][df][r] * inv + x[off + df * 16];
    }
  }
}

// ---- Kernel 3: O projection + residuals, MFMA.
__global__ __launch_bounds__(256) void gemm_out(
    const float* __restrict__ Y,
    const float* __restrict__ wo, const float* __restrict__ bo,
    const float* __restrict__ x, float* __restrict__ out)
{
  __shared__ __align__(16) bf16 As[TM * TK];
  __shared__ __align__(16) bf16 Bs[TN * TK];

  const int tid  = threadIdx.x;
  const int lane = tid & 63, wid = tid >> 6;
  const int wm = (wid >> 1) * 64, wn = (wid & 1) * 64;
  const int row0 = blockIdx.y * TM, col0 = blockIdx.x * TN;
  const int mb = lane & 15;
  const int kq = (lane >> 4) * 8;

  f32x4 acc[4][4];
#pragma unroll
  for (int i = 0; i < 4; ++i)
#pragma unroll
    for (int j = 0; j < 4; ++j) acc[i][j] = (f32x4){0.f, 0.f, 0.f, 0.f};

  for (int k0 = 0; k0 < C_; k0 += TK) {
#pragma unroll
    for (int t = 0; t < 2; ++t) {
      const int c = t * 256 + tid;
      const int row = c >> 2, kc = (c & 3) * 8;
      ((uint4*)As)[c] = ld8f_cvt(Y  + (size_t)(row0 + row) * C_ + k0 + kc);
      ((uint4*)Bs)[c] = ld8f_cvt(wo + (size_t)(col0 + row) * C_ + k0 + kc);
    }
    __syncthreads();
    bf16x8 af[4], bfr[4];
#pragma unroll
    for (int i = 0; i < 4; ++i)
      af[i] = *(const bf16x8*)(As + (wm + i * 16 + mb) * TK + kq);
#pragma unroll
    for (int j = 0; j < 4; ++j)
      bfr[j] = *(const bf16x8*)(Bs + (wn + j * 16 + mb) * TK + kq);
#pragma unroll
    for (int i = 0; i < 4; ++i)
#pragma unroll
      for (int j = 0; j < 4; ++j)
        acc[i][j] = __builtin_amdgcn_mfma_f32_16x16x32_bf16(af[i], bfr[j], acc[i][j], 0, 0, 0);
    __syncthreads();
  }

  const int crow = (lane >> 4) * 4;
#pragma unroll
  for (int j = 0; j < 4; ++j) {
    const int o = col0 + wn + j * 16 + mb;
    const float bb = bo[o];
#pragma unroll
    for (int i = 0; i < 4; ++i) {
#pragma unroll
      for (int reg = 0; reg < 4; ++reg) {
        const int r = row0 + wm + i * 16 + crow + reg;
        const size_t off = (size_t)r * C_ + o;
        out[off] = acc[i][j][reg] + bb + Y[off] + x[off];
      }
    }
  }
}

extern "C" void kernel_launch(void* const* d_in, const int* in_sizes, int n_in,
                              void* d_out, int out_size, void* d_ws, size_t ws_size,
                              hipStream_t stream)
{
  const float* x  = (const float*)d_in[0];
  const float* wq = (const float*)d_in[1];
  const float* bq = (const float*)d_in[2];
  const float* wk = (const float*)d_in[3];
  const float* bk = (const float*)d_in[4];
  const float* wv = (const float*)d_in[5];
  const float* bv = (const float*)d_in[6];
  const float* wo = (const float*)d_in[7];
  const float* bo = (const float*)d_in[8];
  float* out = (float*)d_out;

  const size_t nEl = (size_t)B_ * N_ * C_;
  bf16* Q  = (bf16*)d_ws;                       // [b][h][n][48], pre-scaled
  bf16* K  = Q + nEl;                           // [b][h][n][48]
  bf16* V  = K + nEl;                           // [b][h][n][48]
  bf16* Vt = V + nEl;                           // [b][h][d][n]
  float* Y = (float*)(Vt + nEl);                // [b][n][c] fp32

  dim3 gqkv(C_ / TN, (B_ * N_) / TM, 3);
  gemm_qkv<<<gqkv, dim3(256), 0, stream>>>(x, wq, bq, wk, bk, wv, bv, Q, K, V);

  dim3 gtr(B_ * H_, N_ / 64);                   // (64, 32)
  v_transpose<<<gtr, dim3(256), 0, stream>>>(V, Vt);

  dim3 gattn(B_ * H_, N_ / 128);                // (64, 16)
  attn_mfma<<<gattn, dim3(256), 0, stream>>>(Q, K, Vt, x, Y);

  dim3 gout(C_ / TN, (B_ * N_) / TM);
  gemm_out<<<gout, dim3(256), 0, stream>>>(Y, wo, bo, x, out);
}

// Round 8
// 337.090 us; speedup vs baseline: 1.1150x; 1.1150x over previous
//
#include <hip/hip_runtime.h>
#include <hip/hip_bf16.h>

// B=4, N=2048, C=768, H=16, D=48. FP32 in/out.
// ws: Q,K,V [b][h][...] bf16 stored in MFMA-FRAGMENT layouts after qkv_reshape
// (Q pre-scaled by SCALE*log2e), Y fp32. out = (y@Wo^T+bo)+y+x, y = attn+x
#define B_ 4
#define N_ 2048
#define C_ 768
#define H_ 16
#define D_ 48
#define SCALE_ 0.14433756729740643f
#define LOG2E_ 1.44269504088896f

using bf16 = __hip_bfloat16;
using bf16x8 = __attribute__((ext_vector_type(8))) short;
using f32x4  = __attribute__((ext_vector_type(4))) float;
using f32x16 = __attribute__((ext_vector_type(16))) float;

__device__ __forceinline__ unsigned short f2b(float f) {
  bf16 h = __float2bfloat16(f);
  return *reinterpret_cast<unsigned short*>(&h);
}
__device__ __forceinline__ unsigned int pack2(float lo, float hi) {
  return (unsigned int)f2b(lo) | ((unsigned int)f2b(hi) << 16);
}
__device__ __forceinline__ uint4 ld8f_cvt(const float* p) {
  float4 a = *reinterpret_cast<const float4*>(p);
  float4 b = *reinterpret_cast<const float4*>(p + 4);
  uint4 u;
  u.x = pack2(a.x, a.y); u.y = pack2(a.z, a.w);
  u.z = pack2(b.x, b.y); u.w = pack2(b.z, b.w);
  return u;
}

constexpr int TM = 128, TN = 128, TK = 32;

// ---- Kernel 1: QKV projection, MFMA. z picks Q/K/V. Writes [b][h][n][48].
__global__ __launch_bounds__(256) void gemm_qkv(
    const float* __restrict__ X,
    const float* __restrict__ wq, const float* __restrict__ bq,
    const float* __restrict__ wk, const float* __restrict__ bk,
    const float* __restrict__ wv, const float* __restrict__ bv,
    bf16* __restrict__ Q, bf16* __restrict__ K, bf16* __restrict__ V)
{
  const float* W; const float* bias; bf16* dst;
  if (blockIdx.z == 0)      { W = wq; bias = bq; dst = Q; }
  else if (blockIdx.z == 1) { W = wk; bias = bk; dst = K; }
  else                      { W = wv; bias = bv; dst = V; }
  const float sc = (blockIdx.z == 0) ? (SCALE_ * LOG2E_) : 1.0f;

  __shared__ __align__(16) bf16 As[TM * TK];
  __shared__ __align__(16) bf16 Bs[TN * TK];

  const int tid  = threadIdx.x;
  const int lane = tid & 63, wid = tid >> 6;
  const int wm = (wid >> 1) * 64, wn = (wid & 1) * 64;
  const int row0 = blockIdx.y * TM, col0 = blockIdx.x * TN;
  const int mb = lane & 15;
  const int kq = (lane >> 4) * 8;

  f32x4 acc[4][4];
#pragma unroll
  for (int i = 0; i < 4; ++i)
#pragma unroll
    for (int j = 0; j < 4; ++j) acc[i][j] = (f32x4){0.f, 0.f, 0.f, 0.f};

  for (int k0 = 0; k0 < C_; k0 += TK) {
#pragma unroll
    for (int t = 0; t < 2; ++t) {
      const int c = t * 256 + tid;
      const int row = c >> 2, kc = (c & 3) * 8;
      ((uint4*)As)[c] = ld8f_cvt(X + (size_t)(row0 + row) * C_ + k0 + kc);
      ((uint4*)Bs)[c] = ld8f_cvt(W + (size_t)(col0 + row) * C_ + k0 + kc);
    }
    __syncthreads();
    bf16x8 af[4], bfr[4];
#pragma unroll
    for (int i = 0; i < 4; ++i)
      af[i] = *(const bf16x8*)(As + (wm + i * 16 + mb) * TK + kq);
#pragma unroll
    for (int j = 0; j < 4; ++j)
      bfr[j] = *(const bf16x8*)(Bs + (wn + j * 16 + mb) * TK + kq);
#pragma unroll
    for (int i = 0; i < 4; ++i)
#pragma unroll
      for (int j = 0; j < 4; ++j)
        acc[i][j] = __builtin_amdgcn_mfma_f32_16x16x32_bf16(af[i], bfr[j], acc[i][j], 0, 0, 0);
    __syncthreads();
  }

  const int crow = (lane >> 4) * 4;
#pragma unroll
  for (int j = 0; j < 4; ++j) {
    const int o = col0 + wn + j * 16 + mb;
    const int h = o / D_, d = o % D_;
    const float bb = bias[o];
#pragma unroll
    for (int i = 0; i < 4; ++i) {
#pragma unroll
      for (int reg = 0; reg < 4; ++reg) {
        const int r = row0 + wm + i * 16 + crow + reg;
        const int b_ = r >> 11, n = r & (N_ - 1);
        dst[(((size_t)(b_ * H_ + h)) * N_ + n) * D_ + d] =
            __float2bfloat16((acc[i][j][reg] + bb) * sc);
      }
    }
  }
}

// ---- Kernel 1b: IN-PLACE reshape of Q,K,V into MFMA-fragment layouts.
// Q,K: per 32-row block kg: chunk order [kc(3)][g2(2)][m5(32)] of 8 elems,
//      element (n=kg*32+m5, d=kc*16+g2*8+j) -> so attn's frag load = lane*16B.
// V:   per 64-row block kt: chunk order [df(3)][hf(2)][g4(4)][c(16)],
//      element (n=kt*64+hf*32+g4*8+j, d=df*16+c).
// Both permutations are closed within the 64-row tile -> in-place safe.
__global__ __launch_bounds__(256) void qkv_reshape(
    bf16* __restrict__ Q, bf16* __restrict__ K, bf16* __restrict__ V)
{
  __shared__ short T[64 * 50];   // 50: odd-ish stride for column reads
  const int bh = blockIdx.x;
  const int t0 = blockIdx.y * 64;
  const int tid = threadIdx.x;
  const size_t base = (size_t)bh * (N_ * D_) + (size_t)t0 * D_;
  bf16* bufs[3] = {Q, K, V};
#pragma unroll 1
  for (int wbuf = 0; wbuf < 3; ++wbuf) {
    bf16* P = bufs[wbuf] + base;
    for (int cc = tid; cc < 384; cc += 256) {
      const int r = cc / 6, ch = cc % 6;
      bf16x8 v8 = *(const bf16x8*)(P + r * D_ + ch * 8);
#pragma unroll
      for (int e = 0; e < 8; ++e) T[r * 50 + ch * 8 + e] = v8[e];
    }
    __syncthreads();
    if (wbuf < 2) {
      for (int w = tid; w < 384; w += 256) {
        const int sub = w / 192, rem = w % 192;
        const int kc = rem / 64, rem2 = rem % 64;
        const int g2 = rem2 >> 5, m5 = rem2 & 31;
        bf16x8 o;
#pragma unroll
        for (int e = 0; e < 8; ++e)
          o[e] = T[(sub * 32 + m5) * 50 + kc * 16 + g2 * 8 + e];
        *(bf16x8*)(P + w * 8) = o;        // write addr = base + w*16B: coalesced
      }
    } else {
      for (int w = tid; w < 384; w += 256) {
        const int df = w / 128, rem = w % 128;
        const int hf = rem / 64, rem2 = rem % 64;
        const int g4 = rem2 >> 4, cx = rem2 & 15;
        bf16x8 o;
#pragma unroll
        for (int e = 0; e < 8; ++e)
          o[e] = T[(hf * 32 + g4 * 8 + e) * 50 + df * 16 + cx];
        *(bf16x8*)(P + w * 8) = o;
      }
    }
    __syncthreads();
  }
}

// ---- Kernel 2: barrier-free register flash attention, fragment-layout inputs.
// Every Q/K/V fragment load is base + lane*16B (fully coalesced).
__global__ __launch_bounds__(256) void attn_mfma(
    const bf16* __restrict__ Qf, const bf16* __restrict__ Kf,
    const bf16* __restrict__ Vf, const float* __restrict__ x,
    float* __restrict__ Y)
{
  __shared__ __align__(16) bf16 Ps[4 * 32 * 72];   // per-wave P [qrow][key]

  const int tid  = threadIdx.x;
  const int lane = tid & 63, wid = tid >> 6;
  const int g2 = lane >> 5;          // 32x32 k-half
  const int m5 = lane & 31;          // 32x32 m/n index
  const int g4 = lane >> 4;          // 16x16 k-quad
  const int c  = lane & 15;          // 16x16 m/n index
  const int bh = blockIdx.x;
  const int b_ = bh >> 4, h = bh & 15;
  const int q0 = blockIdx.y * 128 + wid * 32;
  const size_t slab = (size_t)bh * (N_ * D_);
  bf16* Pw = Ps + wid * (32 * 72);

  // Q B-fragments: block kg=q0/32, chunks kc=0..2, offset lane*8 elems
  bf16x8 qf[3];
  const int kgq = q0 >> 5;
#pragma unroll
  for (int kc = 0; kc < 3; ++kc)
    qf[kc] = *(const bf16x8*)(Qf + slab + (size_t)(((kgq * 3 + kc) * 64) + lane) * 8);

  f32x4 Oacc[2][3];
#pragma unroll
  for (int s = 0; s < 2; ++s)
#pragma unroll
    for (int df = 0; df < 3; ++df) Oacc[s][df] = (f32x4){0.f, 0.f, 0.f, 0.f};
  float lsum = 0.f;

  for (int k0 = 0; k0 < N_; k0 += 64) {
    const int kg = k0 >> 5, kt = k0 >> 6;
    bf16x8 kf[2][3];
#pragma unroll
    for (int mt = 0; mt < 2; ++mt)
#pragma unroll
      for (int kc = 0; kc < 3; ++kc)
        kf[mt][kc] = *(const bf16x8*)(Kf + slab +
            (size_t)((((kg + mt) * 3 + kc) * 64) + lane) * 8);
    bf16x8 vf[3][2];
#pragma unroll
    for (int df = 0; df < 3; ++df)
#pragma unroll
      for (int hf = 0; hf < 2; ++hf)
        vf[df][hf] = *(const bf16x8*)(Vf + slab +
            (size_t)(((((kt * 3 + df) * 2 + hf) * 64)) + lane) * 8);

    // S^T = K·Q^T : D[m=key][n=qrow], 2 m-tiles x 3 k-chunks (no padding)
    f32x16 st[2];
#pragma unroll
    for (int mt = 0; mt < 2; ++mt) {
      f32x16 z;
#pragma unroll
      for (int r = 0; r < 16; ++r) z[r] = 0.f;
      st[mt] = __builtin_amdgcn_mfma_f32_32x32x16_bf16(kf[mt][0], qf[0], z, 0, 0, 0);
      st[mt] = __builtin_amdgcn_mfma_f32_32x32x16_bf16(kf[mt][1], qf[1], st[mt], 0, 0, 0);
      st[mt] = __builtin_amdgcn_mfma_f32_32x32x16_bf16(kf[mt][2], qf[2], st[mt], 0, 0, 0);
    }
    // P = exp2(score) (scale*log2e folded into Q)
    float psum = 0.f;
#pragma unroll
    for (int mt = 0; mt < 2; ++mt)
#pragma unroll
      for (int r = 0; r < 16; ++r) {
        st[mt][r] = __builtin_amdgcn_exp2f(st[mt][r]);
        psum += st[mt][r];
      }
    lsum += psum;   // per-lane; other key-half at lane^32, folded at end
    // pack P -> LDS [qrow][key]: regs 4q..4q+3 = keys 8q+4g2+0..3
#pragma unroll
    for (int mt = 0; mt < 2; ++mt)
#pragma unroll
      for (int q = 0; q < 4; ++q) {
        uint2 w;
        w.x = pack2(st[mt][4 * q + 0], st[mt][4 * q + 1]);
        w.y = pack2(st[mt][4 * q + 2], st[mt][4 * q + 3]);
        *(uint2*)(Pw + m5 * 72 + mt * 32 + 8 * q + 4 * g2) = w;
      }
    // PV: A = P [m=qrow 16(+16s)][k=key], B = vf
#pragma unroll
    for (int s = 0; s < 2; ++s) {
      bf16x8 pf[2];
#pragma unroll
      for (int hf = 0; hf < 2; ++hf)
        pf[hf] = *(const bf16x8*)(Pw + (s * 16 + c) * 72 + hf * 32 + 8 * g4);
#pragma unroll
      for (int df = 0; df < 3; ++df) {
        Oacc[s][df] = __builtin_amdgcn_mfma_f32_16x16x32_bf16(pf[0], vf[df][0], Oacc[s][df], 0, 0, 0);
        Oacc[s][df] = __builtin_amdgcn_mfma_f32_16x16x32_bf16(pf[1], vf[df][1], Oacc[s][df], 0, 0, 0);
      }
    }
  }

  const float ltot = lsum + __shfl_xor(lsum, 32, 64);
#pragma unroll
  for (int s = 0; s < 2; ++s) {
#pragma unroll
    for (int r = 0; r < 4; ++r) {
      const float inv = 1.f / __shfl(ltot, s * 16 + 4 * g4 + r, 64);
      const int n = q0 + s * 16 + 4 * g4 + r;
      const size_t off = ((size_t)(b_ * N_ + n)) * C_ + h * D_ + c;
#pragma unroll
      for (int df = 0; df < 3; ++df)
        Y[off + df * 16] = Oacc[s][df][r] * inv + x[off + df * 16];
    }
  }
}

// ---- Kernel 3: O projection + residuals, MFMA.
__global__ __launch_bounds__(256) void gemm_out(
    const float* __restrict__ Y,
    const float* __restrict__ wo, const float* __restrict__ bo,
    const float* __restrict__ x, float* __restrict__ out)
{
  __shared__ __align__(16) bf16 As[TM * TK];
  __shared__ __align__(16) bf16 Bs[TN * TK];

  const int tid  = threadIdx.x;
  const int lane = tid & 63, wid = tid >> 6;
  const int wm = (wid >> 1) * 64, wn = (wid & 1) * 64;
  const int row0 = blockIdx.y * TM, col0 = blockIdx.x * TN;
  const int mb = lane & 15;
  const int kq = (lane >> 4) * 8;

  f32x4 acc[4][4];
#pragma unroll
  for (int i = 0; i < 4; ++i)
#pragma unroll
    for (int j = 0; j < 4; ++j) acc[i][j] = (f32x4){0.f, 0.f, 0.f, 0.f};

  for (int k0 = 0; k0 < C_; k0 += TK) {
#pragma unroll
    for (int t = 0; t < 2; ++t) {
      const int c = t * 256 + tid;
      const int row = c >> 2, kc = (c & 3) * 8;
      ((uint4*)As)[c] = ld8f_cvt(Y  + (size_t)(row0 + row) * C_ + k0 + kc);
      ((uint4*)Bs)[c] = ld8f_cvt(wo + (size_t)(col0 + row) * C_ + k0 + kc);
    }
    __syncthreads();
    bf16x8 af[4], bfr[4];
#pragma unroll
    for (int i = 0; i < 4; ++i)
      af[i] = *(const bf16x8*)(As + (wm + i * 16 + mb) * TK + kq);
#pragma unroll
    for (int j = 0; j < 4; ++j)
      bfr[j] = *(const bf16x8*)(Bs + (wn + j * 16 + mb) * TK + kq);
#pragma unroll
    for (int i = 0; i < 4; ++i)
#pragma unroll
      for (int j = 0; j < 4; ++j)
        acc[i][j] = __builtin_amdgcn_mfma_f32_16x16x32_bf16(af[i], bfr[j], acc[i][j], 0, 0, 0);
    __syncthreads();
  }

  const int crow = (lane >> 4) * 4;
#pragma unroll
  for (int j = 0; j < 4; ++j) {
    const int o = col0 + wn + j * 16 + mb;
    const float bb = bo[o];
#pragma unroll
    for (int i = 0; i < 4; ++i) {
#pragma unroll
      for (int reg = 0; reg < 4; ++reg) {
        const int r = row0 + wm + i * 16 + crow + reg;
        const size_t off = (size_t)r * C_ + o;
        out[off] = acc[i][j][reg] + bb + Y[off] + x[off];
      }
    }
  }
}

extern "C" void kernel_launch(void* const* d_in, const int* in_sizes, int n_in,
                              void* d_out, int out_size, void* d_ws, size_t ws_size,
                              hipStream_t stream)
{
  const float* x  = (const float*)d_in[0];
  const float* wq = (const float*)d_in[1];
  const float* bq = (const float*)d_in[2];
  const float* wk = (const float*)d_in[3];
  const float* bk = (const float*)d_in[4];
  const float* wv = (const float*)d_in[5];
  const float* bv = (const float*)d_in[6];
  const float* wo = (const float*)d_in[7];
  const float* bo = (const float*)d_in[8];
  float* out = (float*)d_out;

  const size_t nEl = (size_t)B_ * N_ * C_;
  bf16* Q  = (bf16*)d_ws;                       // fragment layout after reshape
  bf16* K  = Q + nEl;
  bf16* V  = K + nEl;
  float* Y = (float*)(V + nEl);                 // [b][n][c] fp32

  dim3 gqkv(C_ / TN, (B_ * N_) / TM, 3);
  gemm_qkv<<<gqkv, dim3(256), 0, stream>>>(x, wq, bq, wk, bk, wv, bv, Q, K, V);

  dim3 grs(B_ * H_, N_ / 64);                   // (64, 32), in-place
  qkv_reshape<<<grs, dim3(256), 0, stream>>>(Q, K, V);

  dim3 gattn(B_ * H_, N_ / 128);                // (64, 16)
  attn_mfma<<<gattn, dim3(256), 0, stream>>>(Q, K, V, x, Y);

  dim3 gout(C_ / TN, (B_ * N_) / TM);
  gemm_out<<<gout, dim3(256), 0, stream>>>(Y, wo, bo, x, out);
}

// Round 9
// 272.045 us; speedup vs baseline: 1.3816x; 1.2391x over previous
//
#include <hip/hip_runtime.h>
#include <hip/hip_bf16.h>

// B=4, N=2048, C=768, H=16, D=48. FP32 in/out.
// Pipeline: cvt(x,W->bf16) -> gemm_qkv (fused, global_load_lds) -> qkv_reshape
//           -> attn (frag-layout, ones-column lsum) -> gemm_out.
#define B_ 4
#define N_ 2048
#define C_ 768
#define H_ 16
#define D_ 48
#define SCALE_ 0.14433756729740643f
#define LOG2E_ 1.44269504088896f

using bf16 = __hip_bfloat16;
using bf16x8 = __attribute__((ext_vector_type(8))) short;
using f32x4  = __attribute__((ext_vector_type(4))) float;
using f32x16 = __attribute__((ext_vector_type(16))) float;

__device__ __forceinline__ unsigned short f2b(float f) {
  bf16 h = __float2bfloat16(f);
  return *reinterpret_cast<unsigned short*>(&h);
}
__device__ __forceinline__ unsigned int pack2(float lo, float hi) {
  return (unsigned int)f2b(lo) | ((unsigned int)f2b(hi) << 16);
}
__device__ __forceinline__ uint4 ld8f_cvt(const float* p) {
  float4 a = *reinterpret_cast<const float4*>(p);
  float4 b = *reinterpret_cast<const float4*>(p + 4);
  uint4 u;
  u.x = pack2(a.x, a.y); u.y = pack2(a.z, a.w);
  u.z = pack2(b.x, b.y); u.w = pack2(b.z, b.w);
  return u;
}
// async global->LDS, 16B per lane; LDS dest = l + lane*16B (wave-uniform base)
__device__ __forceinline__ void gload_lds16(const bf16* g, bf16* l) {
  __builtin_amdgcn_global_load_lds(
      (const __attribute__((address_space(1))) unsigned int*)g,
      (__attribute__((address_space(3))) unsigned int*)l, 16, 0, 0);
}

// ---- Kernel 0: fp32 -> bf16 conversions (x, Wq|Wk|Wv stacked, Wo).
__global__ __launch_bounds__(256) void cvt_bf16(
    const float* __restrict__ x,  const float* __restrict__ wq,
    const float* __restrict__ wk, const float* __restrict__ wv,
    const float* __restrict__ wo,
    bf16* __restrict__ xb, bf16* __restrict__ wqkvb, bf16* __restrict__ wob)
{
  const int job = blockIdx.y;
  const float* src; bf16* dst; int n;
  if (job == 0)      { src = x;  dst = xb;              n = B_ * N_ * C_; }
  else if (job == 1) { src = wq; dst = wqkvb;           n = C_ * C_; }
  else if (job == 2) { src = wk; dst = wqkvb + C_ * C_; n = C_ * C_; }
  else if (job == 3) { src = wv; dst = wqkvb + 2 * C_ * C_; n = C_ * C_; }
  else               { src = wo; dst = wob;             n = C_ * C_; }
  const int stride = gridDim.x * 256 * 8;
  for (int i = (blockIdx.x * 256 + threadIdx.x) * 8; i < n; i += stride)
    *(uint4*)(dst + i) = ld8f_cvt(src + i);
}

// ---- Kernel 1: fused QKV GEMM, m97-style. A=xb[8192x768], B=Wqkv[2304x768].
// 128x128 tile, BK=64, global_load_lds staging, XOR-swizzled LDS chunks.
// z = blockIdx.x/6 selects Q/K/V dst (writes [b][h][n][48], Q scaled).
__global__ __launch_bounds__(256) void gemm_qkv(
    const bf16* __restrict__ A, const bf16* __restrict__ Bw,
    const float* __restrict__ bq, const float* __restrict__ bk,
    const float* __restrict__ bv,
    bf16* __restrict__ Q, bf16* __restrict__ K, bf16* __restrict__ V)
{
  __shared__ __align__(16) bf16 As[128 * 64];
  __shared__ __align__(16) bf16 Bs[128 * 64];

  const int tid  = threadIdx.x;
  const int lane = tid & 63, wid = tid >> 6;
  const int wm = (wid >> 1) * 64, wn = (wid & 1) * 64;
  const int row0 = blockIdx.y * 128, col0 = blockIdx.x * 128;
  const int mb = lane & 15, g4 = lane >> 4;
  const int srow = lane >> 3;                    // staging row-in-8
  const int schunk = (lane & 7) ^ (srow & 7);    // swizzled glb k-chunk

  f32x4 acc[4][4];
#pragma unroll
  for (int i = 0; i < 4; ++i)
#pragma unroll
    for (int j = 0; j < 4; ++j) acc[i][j] = (f32x4){0.f, 0.f, 0.f, 0.f};

  for (int k0 = 0; k0 < C_; k0 += 64) {
#pragma unroll
    for (int t = 0; t < 4; ++t) {
      const int rt = wid * 32 + t * 8;
      gload_lds16(A  + (size_t)(row0 + rt + srow) * C_ + k0 + schunk * 8,
                  As + rt * 64);
      gload_lds16(Bw + (size_t)(col0 + rt + srow) * C_ + k0 + schunk * 8,
                  Bs + rt * 64);
    }
    __syncthreads();
#pragma unroll
    for (int ks = 0; ks < 2; ++ks) {
      const int kchunk = ks * 4 + g4;
      bf16x8 af[4], bfr[4];
#pragma unroll
      for (int i = 0; i < 4; ++i) {
        const int row = wm + i * 16 + mb;
        af[i] = *(const bf16x8*)(As + row * 64 + (kchunk ^ (row & 7)) * 8);
      }
#pragma unroll
      for (int j = 0; j < 4; ++j) {
        const int col = wn + j * 16 + mb;
        bfr[j] = *(const bf16x8*)(Bs + col * 64 + (kchunk ^ (col & 7)) * 8);
      }
#pragma unroll
      for (int i = 0; i < 4; ++i)
#pragma unroll
        for (int j = 0; j < 4; ++j)
          acc[i][j] = __builtin_amdgcn_mfma_f32_16x16x32_bf16(af[i], bfr[j], acc[i][j], 0, 0, 0);
    }
    __syncthreads();
  }

  const int z = blockIdx.x / 6;                  // 768/128=6 blocks per proj
  const float* bias = (z == 0) ? bq : (z == 1) ? bk : bv;
  bf16* dst = (z == 0) ? Q : (z == 1) ? K : V;
  const float sc = (z == 0) ? (SCALE_ * LOG2E_) : 1.0f;
  const int crow = g4 * 4;
#pragma unroll
  for (int j = 0; j < 4; ++j) {
    const int oo = col0 - z * 768 + wn + j * 16 + mb;
    const int h = oo / D_, d = oo % D_;
    const float bb = bias[oo];
#pragma unroll
    for (int i = 0; i < 4; ++i) {
#pragma unroll
      for (int reg = 0; reg < 4; ++reg) {
        const int r = row0 + wm + i * 16 + crow + reg;
        const int b_ = r >> 11, n = r & (N_ - 1);
        dst[(((size_t)(b_ * H_ + h)) * N_ + n) * D_ + d] =
            __float2bfloat16((acc[i][j][reg] + bb) * sc);
      }
    }
  }
}

// ---- Kernel 1b: IN-PLACE reshape of Q,K,V into MFMA-fragment layouts.
__global__ __launch_bounds__(256) void qkv_reshape(
    bf16* __restrict__ Q, bf16* __restrict__ K, bf16* __restrict__ V)
{
  __shared__ short T[64 * 50];
  const int bh = blockIdx.x;
  const int t0 = blockIdx.y * 64;
  const int tid = threadIdx.x;
  const size_t base = (size_t)bh * (N_ * D_) + (size_t)t0 * D_;
  bf16* bufs[3] = {Q, K, V};
#pragma unroll 1
  for (int wbuf = 0; wbuf < 3; ++wbuf) {
    bf16* P = bufs[wbuf] + base;
    for (int cc = tid; cc < 384; cc += 256) {
      const int r = cc / 6, ch = cc % 6;
      bf16x8 v8 = *(const bf16x8*)(P + r * D_ + ch * 8);
#pragma unroll
      for (int e = 0; e < 8; ++e) T[r * 50 + ch * 8 + e] = v8[e];
    }
    __syncthreads();
    if (wbuf < 2) {
      for (int w = tid; w < 384; w += 256) {
        const int sub = w / 192, rem = w % 192;
        const int kc = rem / 64, rem2 = rem % 64;
        const int g2 = rem2 >> 5, m5 = rem2 & 31;
        bf16x8 o;
#pragma unroll
        for (int e = 0; e < 8; ++e)
          o[e] = T[(sub * 32 + m5) * 50 + kc * 16 + g2 * 8 + e];
        *(bf16x8*)(P + w * 8) = o;
      }
    } else {
      for (int w = tid; w < 384; w += 256) {
        const int df = w / 128, rem = w % 128;
        const int hf = rem / 64, rem2 = rem % 64;
        const int g4 = rem2 >> 4, cx = rem2 & 15;
        bf16x8 o;
#pragma unroll
        for (int e = 0; e < 8; ++e)
          o[e] = T[(hf * 32 + g4 * 8 + e) * 50 + df * 16 + cx];
        *(bf16x8*)(P + w * 8) = o;
      }
    }
    __syncthreads();
  }
}

// ---- Kernel 2: barrier-free register flash attention.
// K-frag register double-buffer; ones-column MFMA computes row-sums (no VALU
// reduction, no epilogue shuffles). Writes Y as bf16 only.
__global__ __launch_bounds__(256) void attn_mfma(
    const bf16* __restrict__ Qf, const bf16* __restrict__ Kf,
    const bf16* __restrict__ Vf, const float* __restrict__ x,
    bf16* __restrict__ Yb)
{
  __shared__ __align__(16) bf16 Ps[4 * 32 * 72];

  const int tid  = threadIdx.x;
  const int lane = tid & 63, wid = tid >> 6;
  const int m5 = lane & 31;
  const int g4 = lane >> 4, c = lane & 15;
  const int bh = blockIdx.x;
  const int b_ = bh >> 4, h = bh & 15;
  const int q0 = blockIdx.y * 128 + wid * 32;
  const size_t slab = (size_t)bh * (N_ * D_);
  bf16* Pw = Ps + wid * (32 * 72);

  bf16x8 qf[3];
  const int kgq = q0 >> 5;
#pragma unroll
  for (int kc = 0; kc < 3; ++kc)
    qf[kc] = *(const bf16x8*)(Qf + slab + (size_t)(((kgq * 3 + kc) * 64) + lane) * 8);

  const short one_bf = (short)0x3F80;            // bf16 1.0
  const bf16x8 onesf = {one_bf, one_bf, one_bf, one_bf,
                        one_bf, one_bf, one_bf, one_bf};

  f32x4 Oacc[2][3];
  f32x4 Lacc[2];
#pragma unroll
  for (int s = 0; s < 2; ++s) {
    Lacc[s] = (f32x4){0.f, 0.f, 0.f, 0.f};
#pragma unroll
    for (int df = 0; df < 3; ++df) Oacc[s][df] = (f32x4){0.f, 0.f, 0.f, 0.f};
  }

  bf16x8 kf[2][2][3];
  auto loadK = [&](int kk0, int p) {
    const int kg = kk0 >> 5;
#pragma unroll
    for (int mt = 0; mt < 2; ++mt)
#pragma unroll
      for (int kc = 0; kc < 3; ++kc)
        kf[p][mt][kc] = *(const bf16x8*)(Kf + slab +
            (size_t)((((kg + mt) * 3 + kc) * 64) + lane) * 8);
  };
  auto body = [&](int k0c, int p) {
    const int kt = k0c >> 6;
    bf16x8 vf[3][2];
#pragma unroll
    for (int df = 0; df < 3; ++df)
#pragma unroll
      for (int hf = 0; hf < 2; ++hf)
        vf[df][hf] = *(const bf16x8*)(Vf + slab +
            (size_t)((((kt * 3 + df) * 2 + hf) * 64) + lane) * 8);
    f32x16 st[2];
#pragma unroll
    for (int mt = 0; mt < 2; ++mt) {
      f32x16 z;
#pragma unroll
      for (int r = 0; r < 16; ++r) z[r] = 0.f;
      st[mt] = __builtin_amdgcn_mfma_f32_32x32x16_bf16(kf[p][mt][0], qf[0], z, 0, 0, 0);
      st[mt] = __builtin_amdgcn_mfma_f32_32x32x16_bf16(kf[p][mt][1], qf[1], st[mt], 0, 0, 0);
      st[mt] = __builtin_amdgcn_mfma_f32_32x32x16_bf16(kf[p][mt][2], qf[2], st[mt], 0, 0, 0);
    }
#pragma unroll
    for (int mt = 0; mt < 2; ++mt)
#pragma unroll
      for (int r = 0; r < 16; ++r)
        st[mt][r] = __builtin_amdgcn_exp2f(st[mt][r]);
#pragma unroll
    for (int mt = 0; mt < 2; ++mt)
#pragma unroll
      for (int q = 0; q < 4; ++q) {
        uint2 w;
        w.x = pack2(st[mt][4 * q + 0], st[mt][4 * q + 1]);
        w.y = pack2(st[mt][4 * q + 2], st[mt][4 * q + 3]);
        *(uint2*)(Pw + m5 * 72 + mt * 32 + 8 * q + 4 * (lane >> 5)) = w;
      }
#pragma unroll
    for (int s = 0; s < 2; ++s) {
      bf16x8 pf[2];
#pragma unroll
      for (int hf = 0; hf < 2; ++hf)
        pf[hf] = *(const bf16x8*)(Pw + (s * 16 + c) * 72 + hf * 32 + 8 * g4);
#pragma unroll
      for (int df = 0; df < 3; ++df) {
        Oacc[s][df] = __builtin_amdgcn_mfma_f32_16x16x32_bf16(pf[0], vf[df][0], Oacc[s][df], 0, 0, 0);
        Oacc[s][df] = __builtin_amdgcn_mfma_f32_16x16x32_bf16(pf[1], vf[df][1], Oacc[s][df], 0, 0, 0);
      }
      Lacc[s] = __builtin_amdgcn_mfma_f32_16x16x32_bf16(pf[0], onesf, Lacc[s], 0, 0, 0);
      Lacc[s] = __builtin_amdgcn_mfma_f32_16x16x32_bf16(pf[1], onesf, Lacc[s], 0, 0, 0);
    }
  };

  loadK(0, 0);
  for (int k0 = 0; k0 < N_; k0 += 128) {
    loadK(k0 + 64, 1);
    body(k0, 0);
    if (k0 + 128 < N_) loadK(k0 + 128, 0);
    body(k0 + 64, 1);
  }

#pragma unroll
  for (int s = 0; s < 2; ++s) {
#pragma unroll
    for (int r = 0; r < 4; ++r) {
      const float inv = 1.f / Lacc[s][r];
      const int n = q0 + s * 16 + 4 * g4 + r;
      const size_t off = ((size_t)(b_ * N_ + n)) * C_ + h * D_ + c;
#pragma unroll
      for (int df = 0; df < 3; ++df)
        Yb[off + df * 16] =
            __float2bfloat16(Oacc[s][df][r] * inv + x[off + df * 16]);
    }
  }
}

// ---- Kernel 3: O projection + residuals, m97-style staging.
// out[r][o] = acc + bo[o] + float(Yb[r][o]) + x[r][o]
__global__ __launch_bounds__(256) void gemm_out(
    const bf16* __restrict__ Yb, const bf16* __restrict__ Bw,
    const float* __restrict__ bo, const float* __restrict__ x,
    float* __restrict__ out)
{
  __shared__ __align__(16) bf16 As[128 * 64];
  __shared__ __align__(16) bf16 Bs[128 * 64];

  const int tid  = threadIdx.x;
  const int lane = tid & 63, wid = tid >> 6;
  const int wm = (wid >> 1) * 64, wn = (wid & 1) * 64;
  const int row0 = blockIdx.y * 128, col0 = blockIdx.x * 128;
  const int mb = lane & 15, g4 = lane >> 4;
  const int srow = lane >> 3;
  const int schunk = (lane & 7) ^ (srow & 7);

  f32x4 acc[4][4];
#pragma unroll
  for (int i = 0; i < 4; ++i)
#pragma unroll
    for (int j = 0; j < 4; ++j) acc[i][j] = (f32x4){0.f, 0.f, 0.f, 0.f};

  for (int k0 = 0; k0 < C_; k0 += 64) {
#pragma unroll
    for (int t = 0; t < 4; ++t) {
      const int rt = wid * 32 + t * 8;
      gload_lds16(Yb + (size_t)(row0 + rt + srow) * C_ + k0 + schunk * 8,
                  As + rt * 64);
      gload_lds16(Bw + (size_t)(col0 + rt + srow) * C_ + k0 + schunk * 8,
                  Bs + rt * 64);
    }
    __syncthreads();
#pragma unroll
    for (int ks = 0; ks < 2; ++ks) {
      const int kchunk = ks * 4 + g4;
      bf16x8 af[4], bfr[4];
#pragma unroll
      for (int i = 0; i < 4; ++i) {
        const int row = wm + i * 16 + mb;
        af[i] = *(const bf16x8*)(As + row * 64 + (kchunk ^ (row & 7)) * 8);
      }
#pragma unroll
      for (int j = 0; j < 4; ++j) {
        const int col = wn + j * 16 + mb;
        bfr[j] = *(const bf16x8*)(Bs + col * 64 + (kchunk ^ (col & 7)) * 8);
      }
#pragma unroll
      for (int i = 0; i < 4; ++i)
#pragma unroll
        for (int j = 0; j < 4; ++j)
          acc[i][j] = __builtin_amdgcn_mfma_f32_16x16x32_bf16(af[i], bfr[j], acc[i][j], 0, 0, 0);
    }
    __syncthreads();
  }

  const int crow = g4 * 4;
#pragma unroll
  for (int j = 0; j < 4; ++j) {
    const int o = col0 + wn + j * 16 + mb;
    const float bb = bo[o];
#pragma unroll
    for (int i = 0; i < 4; ++i) {
#pragma unroll
      for (int reg = 0; reg < 4; ++reg) {
        const int r = row0 + wm + i * 16 + crow + reg;
        const size_t off = (size_t)r * C_ + o;
        out[off] = acc[i][j][reg] + bb + __bfloat162float(Yb[off]) + x[off];
      }
    }
  }
}

extern "C" void kernel_launch(void* const* d_in, const int* in_sizes, int n_in,
                              void* d_out, int out_size, void* d_ws, size_t ws_size,
                              hipStream_t stream)
{
  const float* x  = (const float*)d_in[0];
  const float* wq = (const float*)d_in[1];
  const float* bq = (const float*)d_in[2];
  const float* wk = (const float*)d_in[3];
  const float* bk = (const float*)d_in[4];
  const float* wv = (const float*)d_in[5];
  const float* bv = (const float*)d_in[6];
  const float* wo = (const float*)d_in[7];
  const float* bo = (const float*)d_in[8];
  float* out = (float*)d_out;

  const size_t nEl = (size_t)B_ * N_ * C_;      // 6,291,456
  const size_t wEl = (size_t)C_ * C_;           // 589,824
  bf16* Q     = (bf16*)d_ws;                    // fragment layout after reshape
  bf16* K     = Q + nEl;
  bf16* V     = K + nEl;
  bf16* Yb    = V + nEl;                        // [b][n][c] bf16 (y = attn+x)
  bf16* xb    = Yb + nEl;                       // [8192][768] bf16
  bf16* wqkvb = xb + nEl;                       // [2304][768] bf16 stacked
  bf16* wob   = wqkvb + 3 * wEl;                // [768][768] bf16

  dim3 gcvt(768, 5);
  cvt_bf16<<<gcvt, dim3(256), 0, stream>>>(x, wq, wk, wv, wo, xb, wqkvb, wob);

  dim3 gqkv(18, 64);                            // 2304/128 x 8192/128
  gemm_qkv<<<gqkv, dim3(256), 0, stream>>>(xb, wqkvb, bq, bk, bv, Q, K, V);

  dim3 grs(B_ * H_, N_ / 64);                   // (64, 32), in-place
  qkv_reshape<<<grs, dim3(256), 0, stream>>>(Q, K, V);

  dim3 gattn(B_ * H_, N_ / 128);                // (64, 16)
  attn_mfma<<<gattn, dim3(256), 0, stream>>>(Q, K, V, x, Yb);

  dim3 gout(6, 64);                             // 768/128 x 8192/128
  gemm_out<<<gout, dim3(256), 0, stream>>>(Yb, wob, bo, x, out);
}